// Round 7
// baseline (143.074 us; speedup 1.0000x reference)
//
#include <hip/hip_runtime.h>

// SSIM (win=11, sigma=1.5, range=255), N=16 C=3 512x512 fp32 -> [16,502,502].
// R7: latency-chain surgery on R6 (all pipes <20% busy, ~8 waves/CU):
//  - 5 separate s_ht buffers (30 kB, free at 2 blocks/CU): ALL 15 H-MFMAs +
//    ds_writes issue first, then all 10 ds_reads + V-MFMAs -- ONE LDS
//    write->read latency wall per channel instead of five, no address
//    aliasing pinning the scheduler.
//  - next channel's 12 global_load_dwordx4 issued right after packing the
//    current fragments (24 float4 = 96 VGPR held -- deliberately smaller
//    than R5's 64-float4 file that spilled); they stay in flight across the
//    whole H+V+SSIM section. launch_bounds(256,2) -> VGPR cap 256.
//  - still zero __syncthreads in the channel loop (waves independent;
//    s_ht regions wave-private, per-wave DS ordering -- validated R3-R6).
//
// MFMA scheme (mfma_f32_16x16x32_f16), B[k][n] = W[k-n] banded, both passes:
//  H: A[m=row][k=col] -> D[m=row][n=outcol]; C-layout (col=lane&15,
//     row=(lane>>4)*4+reg) -> ds_write_b64 transposed into H_T[outcol][row].
//  V: A[m=outcol][k=row] from H_T (k contiguous -> ds_read_b128),
//     D[m=outcol][n=outrow]. Wave owns outcol chunk for both passes.
//  x^2/y^2/xy A-frags derived in registers (v_pk_mul_f16 of x/y frags).
// Edge clamps (uniform min()): clamped rows/cols feed only zero band-weights
// or store-masked outputs (proof in R6 header; R6 passed at absmax 0.0078).

namespace {

constexpr int NN = 16, CC = 3, HH = 512, WW = 512;
constexpr int OH = HH - 10, OW = WW - 10;          // 502 x 502
constexpr int TW = 64, TH = 32;                    // output tile per block
constexpr int HPITCH = 48;                         // H_T row pitch (f16)
constexpr float C1c = 6.5025f;                     // (0.01*255)^2
constexpr float C2c = 58.5225f;                    // (0.03*255)^2

typedef _Float16 half8   __attribute__((ext_vector_type(8)));
typedef _Float16 half4   __attribute__((ext_vector_type(4)));
typedef float    floatv4 __attribute__((ext_vector_type(4)));

__device__ const float WF[11] = {
    0.00102838f, 0.00759876f, 0.03600077f, 0.10936069f, 0.21300553f,
    0.26601172f,
    0.21300553f, 0.10936069f, 0.03600077f, 0.00759876f, 0.00102838f
};

__device__ inline half8 pack8(const float4& a, const float4& b) {
    half8 h = {(_Float16)a.x, (_Float16)a.y, (_Float16)a.z, (_Float16)a.w,
               (_Float16)b.x, (_Float16)b.y, (_Float16)b.z, (_Float16)b.w};
    return h;
}

__global__ __launch_bounds__(256, 2)
void ssim_kernel(const float* __restrict__ X, const float* __restrict__ Y,
                 float* __restrict__ out)
{
    __shared__ __align__(16) _Float16 s_ht[5][TW][HPITCH];  // 30720 B
    __shared__ _Float16 s_wtab[16];

    const int tid  = threadIdx.x;
    const int lane = tid & 63;
    const int wv   = tid >> 6;          // wave id = outcol chunk (16 cols)
    const int col0 = blockIdx.x * TW;
    const int row0 = blockIdx.y * TH;
    const int n    = blockIdx.z;

    if (tid < 16) s_wtab[tid] = (tid < 11) ? (_Float16)WF[tid] : (_Float16)0.f;
    __syncthreads();   // only block-wide sync in the kernel

    // banded weight fragment B[k][n] = W[k-n]; lane: n=lane&15, k=(lane>>4)*8+j
    half8 bfrag;
    {
        const int bn = lane & 15, kq = (lane >> 4) * 8;
        #pragma unroll
        for (int j = 0; j < 8; ++j) {
            int kk = kq + j - bn;
            kk = (kk < 0 || kk > 10) ? 11 : kk;   // index 11 holds 0
            bfrag[j] = s_wtab[kk];
        }
    }

    const int arow = lane & 15;          // A m-row select / V outrow-local
    const int aq   = lane >> 4;          // A k-quad
    const int crow = aq * 4;             // C-layout row base

    // global addresses for this lane's A-fragment loads (uniform clamps)
    int gcol = col0 + wv * 16 + aq * 8;
    gcol = gcol <= WW - 8 ? gcol : WW - 8;         // stays 32B-aligned
    int grow[3];
    #pragma unroll
    for (int rc = 0; rc < 3; ++rc) {
        int g = row0 + rc * 16 + arow;
        grow[rc] = g < HH ? g : HH - 1;
    }

    float acc[2][4] = {{0.f,0.f,0.f,0.f},{0.f,0.f,0.f,0.f}};

    const size_t plane = (size_t)HH * WW;
    const float* Xn = X + (size_t)n * CC * plane;
    const float* Yn = Y + (size_t)n * CC * plane;
    const floatv4 zf = {0.f, 0.f, 0.f, 0.f};

    // prefetch register file (24 float4 = 96 VGPR; R5's 64-float4 spilled)
    float4 fx[3][2], fy[3][2];
    #pragma unroll
    for (int rc = 0; rc < 3; ++rc) {
        const float* bx = Xn + (size_t)grow[rc] * WW + gcol;
        const float* by = Yn + (size_t)grow[rc] * WW + gcol;
        fx[rc][0] = *(const float4*)bx;
        fx[rc][1] = *(const float4*)(bx + 4);
        fy[rc][0] = *(const float4*)by;
        fy[rc][1] = *(const float4*)(by + 4);
    }

    #pragma unroll
    for (int ch = 0; ch < CC; ++ch) {
        // ---- pack current channel's fragments (consumes fx/fy) ----
        half8 axf[3], ayf[3];
        #pragma unroll
        for (int rc = 0; rc < 3; ++rc) {
            axf[rc] = pack8(fx[rc][0], fx[rc][1]);
            ayf[rc] = pack8(fy[rc][0], fy[rc][1]);
        }

        // ---- issue next channel's loads; in flight across H+V+SSIM ----
        if (ch + 1 < CC) {
            const float* Xc = Xn + (size_t)(ch + 1) * plane;
            const float* Yc = Yn + (size_t)(ch + 1) * plane;
            #pragma unroll
            for (int rc = 0; rc < 3; ++rc) {
                const float* bx = Xc + (size_t)grow[rc] * WW + gcol;
                const float* by = Yc + (size_t)grow[rc] * WW + gcol;
                fx[rc][0] = *(const float4*)bx;
                fx[rc][1] = *(const float4*)(bx + 4);
                fy[rc][0] = *(const float4*)by;
                fy[rc][1] = *(const float4*)(by + 4);
            }
        }

        // ---- H phase: all 15 MFMAs + 15 ds_writes, no interleaved reads ----
        #pragma unroll
        for (int q = 0; q < 5; ++q) {
            #pragma unroll
            for (int rc = 0; rc < 3; ++rc) {
                half8 a;
                if      (q == 0) a = axf[rc];
                else if (q == 1) a = ayf[rc];
                else if (q == 2) a = axf[rc] * axf[rc];
                else if (q == 3) a = ayf[rc] * ayf[rc];
                else             a = axf[rc] * ayf[rc];
                floatv4 d = __builtin_amdgcn_mfma_f32_16x16x32_f16(
                    a, bfrag, zf, 0, 0, 0);
                half4 h = {(_Float16)d[0], (_Float16)d[1],
                           (_Float16)d[2], (_Float16)d[3]};
                *(half4*)&s_ht[q][wv*16 + arow][rc*16 + crow] = h;
            }
        }

        // ---- V phase: 10 ds_reads + 10 V-MFMAs + SSIM ----
        #pragma unroll
        for (int b = 0; b < 2; ++b) {
            floatv4 vf[5];
            #pragma unroll
            for (int q = 0; q < 5; ++q) {
                half8 av = *(const half8*)
                    &s_ht[q][wv*16 + arow][b*16 + aq*8];
                vf[q] = __builtin_amdgcn_mfma_f32_16x16x32_f16(
                    av, bfrag, zf, 0, 0, 0);
            }
            #pragma unroll
            for (int p = 0; p < 4; ++p) {
                float m1 = vf[0][p], m2 = vf[1][p];
                float exx = vf[2][p], eyy = vf[3][p], exy = vf[4][p];
                float m1s = m1*m1, m2s = m2*m2, m12 = m1*m2;
                float s1 = exx - m1s, s2 = eyy - m2s, s12 = exy - m12;
                float n1 = 2.f*m12 + C1c, d1 = m1s + m2s + C1c;
                float n2 = 2.f*s12 + C2c, d2 = s1 + s2 + C2c;
                acc[b][p] = fmaf(n1 * n2, __builtin_amdgcn_rcpf(d1 * d2),
                                 acc[b][p]);
            }
        }
    }

    // ---- epilogue: 1 - mean over channels ----
    #pragma unroll
    for (int b = 0; b < 2; ++b) {
        const int orow = row0 + b*16 + arow;
        const int ocol = col0 + wv*16 + crow;
        if (orow < OH) {
            float r0v = 1.f - acc[b][0] * (1.f/3.f);
            float r1v = 1.f - acc[b][1] * (1.f/3.f);
            float r2v = 1.f - acc[b][2] * (1.f/3.f);
            float r3v = 1.f - acc[b][3] * (1.f/3.f);
            size_t base = ((size_t)n * OH + orow) * OW + ocol;
            if (ocol + 3 < OW) {
                *(float2*)(out + base)     = make_float2(r0v, r1v);
                *(float2*)(out + base + 2) = make_float2(r2v, r3v);
            } else {
                float rs[4] = {r0v, r1v, r2v, r3v};
                #pragma unroll
                for (int p = 0; p < 4; ++p)
                    if (ocol + p < OW) out[base + p] = rs[p];
            }
        }
    }
}

} // namespace

extern "C" void kernel_launch(void* const* d_in, const int* in_sizes, int n_in,
                              void* d_out, int out_size, void* d_ws, size_t ws_size,
                              hipStream_t stream) {
    const float* X = (const float*)d_in[0];
    const float* Y = (const float*)d_in[1];
    float* out = (float*)d_out;

    dim3 grid((OW + TW - 1) / TW,   // 8
              (OH + TH - 1) / TH,   // 16
              NN);                  // 16
    ssim_kernel<<<grid, 256, 0, stream>>>(X, Y, out);
}